// Round 5
// baseline (76.746 us; speedup 1.0000x reference)
//
#include <hip/hip_runtime.h>

// SKANLinear: y[b,o] = sum_{i=0}^{IN} weight[o,i] * sin(w[o,i] * x_ext[b,i])
// x_ext[b,IN] = 1.0. B=2048, IN=256, OUT=256. f32.
//
// R5 = R4 skeleton (lane = b, wave = uniform o-pair, weights via scalar
// pipe, per-lane full sums, no shuffles) with the lgkmcnt exposure fixed:
//  - x tile chunk staged in XOR-swizzled float4 layout: (r,c4) at
//    lx4[r*8 + (c4 ^ (r&7))]. 16B-aligned, bank-even for both the
//    coalesced staging writes and the per-lane row readback.
//  - readback = 8 x ds_read_b128 per chunk (was 64 x ds_read_b32).
//  - chunk 64 -> 32: whole-chunk w/g scalar batch fits SGPRs, xs[32]
//    frees VGPRs for deeper scheduling.
// Inner loop: v_mul(s,v) + v_sin + v_fma(s,v,v) = 12 cyc/elem, VALU floor
// ~10.2 us at 4 waves/SIMD (grid 1024 blocks = 4/CU).

#define IN_DIM 256
#define OUT_DIM 256
#define LDW 257
#define CH 32             // i-chunk width
#define INV_2PI 0.15915494309189535f

__global__ __launch_bounds__(256, 4)
void skan_kernel(const float* __restrict__ x,      // [2048][256]
                 const float* __restrict__ weight, // [256][257]
                 const float* __restrict__ wfreq,  // [256][257]
                 float* __restrict__ y)            // [2048][256]
{
    __shared__ float4 lx4[64 * 8];   // one 64b x 32i chunk, swizzled, 8 KB

    const int t  = threadIdx.x;
    const int l  = t & 63;                                   // lane = local b
    const int wv = __builtin_amdgcn_readfirstlane(t >> 6);   // wave id, uniform

    const int obase = (blockIdx.x & 31) * 8;
    const int b0    = (blockIdx.x >> 5) * 64;

    const int o0 = obase + wv * 2;
    const int o1 = o0 + 1;
    const float* __restrict__ w0r = wfreq  + o0 * LDW;  // uniform -> s_load
    const float* __restrict__ g0r = weight + o0 * LDW;
    const float* __restrict__ w1r = wfreq  + o1 * LDW;
    const float* __restrict__ g1r = weight + o1 * LDW;

    // bias column (i=256, x_ext=1): each lane owns full (b,o) sums.
    float acc0 = g0r[IN_DIM] * __builtin_amdgcn_sinf(w0r[IN_DIM] * INV_2PI);
    float acc1 = g1r[IN_DIM] * __builtin_amdgcn_sinf(w1r[IN_DIM] * INV_2PI);

    // stage chunk ic: 512 float4 by 256 threads (2 each), coalesced reads,
    // swizzled 16B-aligned LDS writes, pre-scaled by 1/(2pi) for v_sin_f32.
    auto stage = [&](int ic) {
#pragma unroll
        for (int k = 0; k < 2; ++k) {
            const int f  = t + k * 256;
            const int r  = f >> 3;       // local b row
            const int c4 = f & 7;        // float4 block within chunk
            float4 v = *(const float4*)(x + (b0 + r) * IN_DIM + ic * CH + c4 * 4);
            v.x *= INV_2PI; v.y *= INV_2PI; v.z *= INV_2PI; v.w *= INV_2PI;
            lx4[r * 8 + (c4 ^ (r & 7))] = v;
        }
    };

    stage(0);

    for (int ic = 0; ic < 8; ++ic) {
        __syncthreads();

        // readback my b-row: 8 x ds_read_b128, bank-even via swizzle
        float xs[CH];
#pragma unroll
        for (int c4 = 0; c4 < 8; ++c4) {
            const float4 v = lx4[l * 8 + (c4 ^ (l & 7))];
            xs[c4 * 4 + 0] = v.x; xs[c4 * 4 + 1] = v.y;
            xs[c4 * 4 + 2] = v.z; xs[c4 * 4 + 3] = v.w;
        }

        __syncthreads();

        if (ic < 7) stage(ic + 1);   // overlap staging with compute

        // pure-VALU inner: w/g wave-uniform (SGPR operands), xs in VGPRs
        const int ib = ic * CH;
#pragma unroll
        for (int j = 0; j < CH; ++j) {
            const float xv = xs[j];
            acc0 = fmaf(g0r[ib + j], __builtin_amdgcn_sinf(w0r[ib + j] * xv), acc0);
            acc1 = fmaf(g1r[ib + j], __builtin_amdgcn_sinf(w1r[ib + j] * xv), acc1);
        }
    }

    y[(b0 + l) * OUT_DIM + o0] = acc0;
    y[(b0 + l) * OUT_DIM + o1] = acc1;
}

extern "C" void kernel_launch(void* const* d_in, const int* in_sizes, int n_in,
                              void* d_out, int out_size, void* d_ws, size_t ws_size,
                              hipStream_t stream) {
    const float* x      = (const float*)d_in[0];
    const float* weight = (const float*)d_in[1];
    const float* wfreq  = (const float*)d_in[2];
    float* y            = (float*)d_out;

    const int B = in_sizes[0] / IN_DIM;            // 2048
    const int grid = (B / 64) * (OUT_DIM / 8);     // 32 * 32 = 1024

    skan_kernel<<<grid, 256, 0, stream>>>(x, weight, wfreq, y);
}